// Round 7
// baseline (1418.815 us; speedup 1.0000x reference)
//
#include <hip/hip_runtime.h>
#include <math.h>

#define Bsz 512
#define Fsz 64
#define Hsz 256
#define TSTEPS 128
#define G3 768

#define BG 16            // batch groups (32 rows each)
#define HB 8             // hidden-slice blocks (32 cols x 3 gates each)
#define NBLK 128
#define NTHR 512         // 8 waves: wv = kq*2 + m  (m = M-half, kq = K-quarter)

// LDS map:
//   s_red : [2 buf][8 wv][8 slot][64 lanes] f32x4 = 131072 B (slot = gate*2 + n2)
//   s_aux : 16B units. enc: x-weights hi u=0..11 (u=gate*4+n2*2+kx), lo 12+u (24KB)
//           dec: regW hi u=0..7 (u=kq*2+kt), lo 8+u (16KB)
//   s_out : [2 buf][4 kq][64] f32x4 (8KB) at OFF_AUX+16KB (decoder only; enc x-weights dead)
//   s_bias: 256 floats
#define OFF_AUX   131072
#define OFF_OUT   (OFF_AUX + 16*1024)
#define OFF_B     (OFF_AUX + 24*1024)
#define SMEM_BYTES (OFF_B + 1024)

typedef float f32x4 __attribute__((ext_vector_type(4)));
typedef short s16x8 __attribute__((ext_vector_type(8)));
typedef unsigned int  u32x4 __attribute__((ext_vector_type(4)));

#define MF(a,b,c) __builtin_amdgcn_mfma_f32_16x16x32_bf16(a,b,c,0,0,0)

static __device__ __forceinline__ unsigned short bf16_rne(float f){
    union { float f; unsigned u; } v; v.f = f;
    return (unsigned short)((v.u + 0x7FFFu + ((v.u >> 16) & 1u)) >> 16);
}
static __device__ __forceinline__ float bf16_to_f(unsigned short h){
    union { unsigned u; float f; } v; v.u = ((unsigned)h) << 16; return v.f;
}
static __device__ __forceinline__ void split8(const float* p, s16x8& hi, s16x8& lo){
    #pragma unroll
    for (int t = 0; t < 8; ++t){
        float f = p[t];
        unsigned short h = bf16_rne(f);
        hi[t] = (short)h;
        lo[t] = (short)bf16_rne(f - bf16_to_f(h));
    }
}
// fast transcendentals (verified R4: absmax unchanged)
static __device__ __forceinline__ float sigmoidf_(float v){
    return __builtin_amdgcn_rcpf(1.0f + __builtin_amdgcn_exp2f(-1.44269504f*v));
}
static __device__ __forceinline__ float tanhf_(float v){
    return 1.0f - 2.0f*__builtin_amdgcn_rcpf(1.0f + __builtin_amdgcn_exp2f(2.88539008f*v));
}

// ---- MALL-coherent (cache-bypass) ops: sc0 sc1 = system scope ----
__device__ __forceinline__ u32x4 load_sys_b128u(const unsigned* p){
    u32x4 r;
    asm volatile("global_load_dwordx4 %0, %1, off sc0 sc1" : "=v"(r) : "v"(p) : "memory");
    return r;
}
__device__ __forceinline__ void store_sys_b32u(unsigned* p, unsigned v){
    asm volatile("global_store_dword %0, %1, off sc0 sc1" :: "v"(p), "v"(v) : "memory");
}
__device__ __forceinline__ int load_sys_i32(const int* p){
    int r;
    asm volatile("global_load_dword %0, %1, off sc0 sc1\n\ts_waitcnt vmcnt(0)"
                 : "=v"(r) : "v"(p) : "memory");
    return r;
}
__device__ __forceinline__ void waitcnt0(){ asm volatile("s_waitcnt vmcnt(0)" ::: "memory"); }
__device__ __forceinline__ void regbar(u32x4& v){ asm volatile("" : "+v"(v)); }

static __device__ __forceinline__ void unpack8(const u32x4 a, const u32x4 b, s16x8& hi, s16x8& lo){
    #pragma unroll
    for (int e = 0; e < 4; ++e){
        hi[e]   = (short)(a[e] >> 16);  lo[e]   = (short)(a[e] & 0xFFFFu);
        hi[4+e] = (short)(b[e] >> 16);  lo[4+e] = (short)(b[e] & 0xFFFFu);
    }
}

// ---------------- setup: M = dec_Wih@reg_W, cfold = dec_Wih@reg_b + dec_bih,
// ---------------- gi0 = x[:,127,:]@dec_Wih.T + dec_bih
extern "C" __global__ void gru_setup(const float* __restrict__ x,
                                     const float* __restrict__ dWih,
                                     const float* __restrict__ dbih,
                                     const float* __restrict__ regW,
                                     const float* __restrict__ regb,
                                     float* __restrict__ Mw,
                                     float* __restrict__ cfold,
                                     float* __restrict__ gi0)
{
    int idx = blockIdx.x*blockDim.x + threadIdx.x;
    if (idx < G3*Hsz) {
        int g = idx >> 8, j = idx & 255;
        float a = 0.f;
        #pragma unroll 8
        for (int f = 0; f < Fsz; ++f) a += dWih[g*Fsz + f]*regW[f*Hsz + j];
        Mw[idx] = a;
    } else if (idx < G3*Hsz + G3) {
        int g = idx - G3*Hsz;
        float a = dbih[g];
        #pragma unroll 8
        for (int f = 0; f < Fsz; ++f) a += dWih[g*Fsz + f]*regb[f];
        cfold[g] = a;
    } else {
        int e = idx - (G3*Hsz + G3);
        if (e < Bsz*G3) {
            int b = e / G3, g = e - b*G3;
            const float* xp = x + (size_t)b*(256*64) + 127*64;
            float a = dbih[g];
            #pragma unroll 8
            for (int f = 0; f < Fsz; ++f) a += xp[f]*dWih[g*Fsz + f];
            gi0[e] = a;
        }
    }
}

// ---------------- persistent GRU: 8 fat blocks per bg (half the MALL reads) ----------------
// h word = hi_bf16<<16 | (lo_bf16 & ~3) | tag2, tag2 = (gen>>1)&3, slot = gen&1.
// Protocol (R4): speculative frag loads + tag check; on miss, flag-gate on the 16
// producer-wave flags of the 2 blocks covering this wave's K-quarter, then miss-only
// reload. Ring-2 safety: block writes gen g+2 only after B1(g+1), which requires all
// its waves validated gen g+1 across ALL 8 producer blocks (union of kq-quarters),
// implying every block passed B1(g), i.e. finished reading gen g.
extern "C" __global__ void __launch_bounds__(NTHR, 1)
gru_persistent(const float* __restrict__ x,
               const float* __restrict__ eWih, const float* __restrict__ eWhh,
               const float* __restrict__ ebih, const float* __restrict__ ebhh,
               const float* __restrict__ dWhh, const float* __restrict__ dbhh,
               const float* __restrict__ Mw,   const float* __restrict__ cfold,
               const float* __restrict__ gi0,  const float* __restrict__ regW,
               const float* __restrict__ regb,
               unsigned* __restrict__ hbuf, unsigned* __restrict__ canary,
               float* __restrict__ out)
{
    extern __shared__ char lds[];
    f32x4* s_red  = (f32x4*)lds;
    s16x8* s_aux  = (s16x8*)(lds + OFF_AUX);
    f32x4* s_outv = (f32x4*)(lds + OFF_OUT);
    float* s_bias = (float*)(lds + OFF_B);

    const int tid  = threadIdx.x;
    const int wv   = tid >> 6;
    const int lane = tid & 63;
    const int quad = lane >> 4;
    const int lcol = lane & 15;
    const int m    = wv & 1;          // M-half (rows m*16..+16)
    const int kq   = wv >> 1;         // K-quarter (cols kq*64..+64)
    const int bg   = blockIdx.x & 15;
    const int hb   = blockIdx.x >> 4; // 0..7
    const int m_o  = hb >> 2, nc = hb & 3;   // out-GEMM tile assignment
    const int n2e  = kq >> 1;         // EW col-half
    const int jb2  = (kq & 1)*2;      // EW row-pair base within quad
    const int r0   = m*16 + quad*4 + jb2;    // this thread's 2 EW rows: r0, r0+1
    const int colL = n2e*16 + lcol;          // local col 0..31
    const int ce   = hb*32 + colL;           // global hidden col
    const f32x4 z4 = {0.f,0.f,0.f,0.f};

    unsigned* mycan = canary + bg*64 + hb*8 + wv;
    const int* fp = (const int*)canary + bg*64 + (kq*2 + ((lane>>3)&1))*8 + (lane & 7);

    // ---- encoder Whh register fragments [gate][n2][kt] ----
    s16x8 wfh[3][2][2], wfl[3][2][2];
    #pragma unroll
    for (int gg = 0; gg < 3; ++gg)
        #pragma unroll
        for (int n2 = 0; n2 < 2; ++n2)
            #pragma unroll
            for (int kt = 0; kt < 2; ++kt)
                split8(eWhh + (size_t)(gg*256 + hb*32 + n2*16 + lcol)*256 + kq*64 + kt*32 + quad*8,
                       wfh[gg][n2][kt], wfl[gg][n2][kt]);
    s16x8 mfh[2][2], mfl[2][2];   // decoder M_n [n2][kt]

    // enc x-weights -> LDS
    for (int u = wv; u < 12; u += 8){
        int gg = u >> 2, n2 = (u >> 1) & 1, kx = u & 1;
        s16x8 hi, lo;
        split8(eWih + (size_t)(gg*256 + hb*32 + n2*16 + lcol)*64 + kx*32 + quad*8, hi, lo);
        s_aux[u*64 + lane] = hi;
        s_aux[(12+u)*64 + lane] = lo;
    }
    if (tid < 32){
        int c = hb*32 + tid;
        s_bias[tid]     = ebih[c]     + ebhh[c];
        s_bias[32+tid]  = ebih[256+c] + ebhh[256+c];
        s_bias[64+tid]  = ebih[512+c];
        s_bias[96+tid]  = ebhh[512+c];
    }
    __syncthreads();

    float hold0 = 0.f, hold1 = 0.f;   // self-produced h-old (registers, h^0 = 0)

    for (int g = 0; g <= 2*TSTEPS; ++g){
        const bool enc  = (g < TSTEPS);
        const bool last = (g == 2*TSTEPS);
        const int  p    = g & 1;
        const unsigned tag  = (unsigned)((g >> 1) & 3);
        const unsigned otag = (unsigned)(((g+1) >> 1) & 3);
        const unsigned* hin = hbuf + (size_t)(g & 1)*Bsz*Hsz;
        unsigned* hout = hbuf + (size_t)((g+1) & 1)*Bsz*Hsz;

        float gr0=0.f, gz0=0.f, gn0=0.f, gr1=0.f, gz1=0.f, gn1=0.f;

        // ---- enc->dec transition ----
        if (g == TSTEPS){
            __syncthreads();   // protect s_bias/s_aux rewrite vs EW(g-1) readers
            #pragma unroll
            for (int gg = 0; gg < 3; ++gg)
                #pragma unroll
                for (int n2 = 0; n2 < 2; ++n2)
                    #pragma unroll
                    for (int kt = 0; kt < 2; ++kt)
                        split8(dWhh + (size_t)(gg*256 + hb*32 + n2*16 + lcol)*256 + kq*64 + kt*32 + quad*8,
                               wfh[gg][n2][kt], wfl[gg][n2][kt]);
            #pragma unroll
            for (int n2 = 0; n2 < 2; ++n2)
                #pragma unroll
                for (int kt = 0; kt < 2; ++kt)
                    split8(Mw + (size_t)(512 + hb*32 + n2*16 + lcol)*256 + kq*64 + kt*32 + quad*8,
                           mfh[n2][kt], mfl[n2][kt]);
            {   // regW -> LDS (unit u = wv: kq_u = wv>>1, kt_u = wv&1)
                s16x8 hi, lo;
                split8(regW + (size_t)(nc*16 + lcol)*256 + (wv>>1)*64 + (wv&1)*32 + quad*8, hi, lo);
                s_aux[wv*64 + lane] = hi;
                s_aux[(8+wv)*64 + lane] = lo;
            }
            if (tid < 32){
                int c = hb*32 + tid;
                s_bias[tid]     = cfold[c]     + dbhh[c];
                s_bias[32+tid]  = cfold[256+c] + dbhh[256+c];
                s_bias[64+tid]  = cfold[512+c];
                s_bias[96+tid]  = dbhh[512+c];
                s_bias[128+tid] = dbhh[c];
                s_bias[160+tid] = dbhh[256+c];
            }
            if (tid < 16) s_bias[192+tid] = regb[nc*16 + tid];
            __syncthreads();
            // gi0 prefetch for this thread's 2 cells
            const float* gp0 = gi0 + (size_t)(bg*32 + r0)*G3 + hb*32 + colL;
            gr0 = gp0[0]; gz0 = gp0[256]; gn0 = gp0[512];
            gr1 = gp0[G3]; gz1 = gp0[G3+256]; gn1 = gp0[G3+512];
        }
        if (g == TSTEPS + 1){
            // fold M into Whh for R,Z gates
            #pragma unroll
            for (int gg = 0; gg < 2; ++gg)
                #pragma unroll
                for (int n2 = 0; n2 < 2; ++n2)
                    #pragma unroll
                    for (int kt = 0; kt < 2; ++kt){
                        float tmp[8];
                        size_t o = (size_t)(gg*256 + hb*32 + n2*16 + lcol)*256 + kq*64 + kt*32 + quad*8;
                        #pragma unroll
                        for (int t2 = 0; t2 < 8; ++t2) tmp[t2] = dWhh[o+t2] + Mw[o+t2];
                        split8(tmp, wfh[gg][n2][kt], wfl[gg][n2][kt]);
                    }
        }

        // ---- accumulators (biases added at EW) ----
        f32x4 aR[2], aZ[2], aNi[2], aNh[2], oa;
        aR[0]=z4; aR[1]=z4; aZ[0]=z4; aZ[1]=z4;
        aNi[0]=z4; aNi[1]=z4; aNh[0]=z4; aNh[1]=z4; oa=z4;

        // ---- SPECULATIVE A-fragment loads (4 x dwordx4) ----
        const unsigned* ab = hin + (size_t)(bg*32 + m*16 + lcol)*256 + kq*64 + quad*8;
        u32x4 t[4];
        t[0] = load_sys_b128u(ab);
        t[1] = load_sys_b128u(ab + 4);
        t[2] = load_sys_b128u(ab + 32);
        t[3] = load_sys_b128u(ab + 36);

        // ---- x-GEMM while fragments fly (enc; waves kq<2, kx=kq) ----
        if (enc && kq < 2){
            const float* xp = x + (size_t)(bg*32 + m*16 + lcol)*(256*64) + (size_t)g*64 + kq*32 + quad*8;
            f32x4 xv0 = *(const f32x4*)xp, xv1 = *(const f32x4*)(xp + 4);
            float xf[8];
            #pragma unroll
            for (int e = 0; e < 4; ++e){ xf[e] = xv0[e]; xf[4+e] = xv1[e]; }
            s16x8 xh, xl;
            split8(xf, xh, xl);
            #pragma unroll
            for (int n2 = 0; n2 < 2; ++n2){
                s16x8 bh, bl;
                bh = s_aux[(n2*2+kq)*64 + lane];      bl = s_aux[(12+n2*2+kq)*64 + lane];
                aR[n2]=MF(xh,bh,aR[n2]); aR[n2]=MF(xh,bl,aR[n2]); aR[n2]=MF(xl,bh,aR[n2]);
                bh = s_aux[(4+n2*2+kq)*64 + lane];    bl = s_aux[(16+n2*2+kq)*64 + lane];
                aZ[n2]=MF(xh,bh,aZ[n2]); aZ[n2]=MF(xh,bl,aZ[n2]); aZ[n2]=MF(xl,bh,aZ[n2]);
                bh = s_aux[(8+n2*2+kq)*64 + lane];    bl = s_aux[(20+n2*2+kq)*64 + lane];
                aNi[n2]=MF(xh,bh,aNi[n2]); aNi[n2]=MF(xh,bl,aNi[n2]); aNi[n2]=MF(xl,bh,aNi[n2]);
            }
        }

        // ---- tag validation: fast path = one drain + one check ----
        #define UPD() { \
            _Pragma("unroll") \
            for (int i = 0; i < 4; ++i) \
                if (!((done >> i) & 1u)){ \
                    unsigned xx = (t[i][0]^tag)|(t[i][1]^tag)|(t[i][2]^tag)|(t[i][3]^tag); \
                    if ((xx & 3u) == 0u) done |= (1u << i); } }
        {
            unsigned done = 0;
            waitcnt0();
            #pragma unroll
            for (int i = 0; i < 4; ++i) regbar(t[i]);
            UPD();
            if (!__all((int)(done == 0xFu))){
                // flag gate on the 16 relevant producer-wave flags
                int v = (int)g;
                while (1){
                    if (lane < 16) v = load_sys_i32(fp);
                    if (__all((int)((lane >= 16) | (v >= (int)g)))) break;
                    __builtin_amdgcn_s_sleep(1);
                }
                while (1){
                    if (!((done >> 0) & 1u)) t[0] = load_sys_b128u(ab);
                    if (!((done >> 1) & 1u)) t[1] = load_sys_b128u(ab + 4);
                    if (!((done >> 2) & 1u)) t[2] = load_sys_b128u(ab + 32);
                    if (!((done >> 3) & 1u)) t[3] = load_sys_b128u(ab + 36);
                    waitcnt0();
                    #pragma unroll
                    for (int i = 0; i < 4; ++i) regbar(t[i]);
                    UPD();
                    if (__all((int)(done == 0xFu))) break;
                    __builtin_amdgcn_s_sleep(1);
                }
            }
        }
        #undef UPD

        // ---- h-GEMMs on this wave's (m, kq) slice ----
        #pragma unroll
        for (int kt = 0; kt < 2; ++kt){
            s16x8 ah, al;
            unpack8(t[kt*2], t[kt*2+1], ah, al);
            if (!last){
                #pragma unroll
                for (int n2 = 0; n2 < 2; ++n2){
                    aR[n2]=MF(ah,wfh[0][n2][kt],aR[n2]); aR[n2]=MF(ah,wfl[0][n2][kt],aR[n2]); aR[n2]=MF(al,wfh[0][n2][kt],aR[n2]);
                    aZ[n2]=MF(ah,wfh[1][n2][kt],aZ[n2]); aZ[n2]=MF(ah,wfl[1][n2][kt],aZ[n2]); aZ[n2]=MF(al,wfh[1][n2][kt],aZ[n2]);
                    aNh[n2]=MF(ah,wfh[2][n2][kt],aNh[n2]); aNh[n2]=MF(ah,wfl[2][n2][kt],aNh[n2]); aNh[n2]=MF(al,wfh[2][n2][kt],aNh[n2]);
                    if (!enc && g > TSTEPS){
                        aNi[n2]=MF(ah,mfh[n2][kt],aNi[n2]); aNi[n2]=MF(ah,mfl[n2][kt],aNi[n2]); aNi[n2]=MF(al,mfh[n2][kt],aNi[n2]);
                    }
                }
            }
            if (g >= TSTEPS + 1 && m == m_o){
                s16x8 bh = s_aux[(kq*2+kt)*64 + lane];
                s16x8 bl = s_aux[(8+kq*2+kt)*64 + lane];
                oa = MF(ah,bh,oa); oa = MF(ah,bl,oa); oa = MF(al,bh,oa);
            }
        }

        // ---- K-reduction partials (double-buffered; ONE barrier/step) ----
        if (!last){
            f32x4* bp = s_red + (size_t)((p*8 + wv)*8)*64 + lane;
            bp[0]   = aR[0];  bp[64]  = aR[1];
            bp[128] = aZ[0];  bp[192] = aZ[1];
            bp[256] = aNi[0]; bp[320] = aNi[1];
            bp[384] = aNh[0]; bp[448] = aNh[1];
        }
        if (g >= TSTEPS + 1 && m == m_o)
            s_outv[(size_t)(p*4 + kq)*64 + lane] = oa;
        __syncthreads();   // B1

        // ---- elementwise (2 cells/thread) + tagged h stores + flag ----
        if (!last){
            f32x4 R = z4, Z = z4, Ni = z4, Nh = z4;
            #pragma unroll
            for (int k2 = 0; k2 < 4; ++k2){
                const f32x4* bp = s_red + (size_t)((p*8 + (k2*2+m))*8)*64 + lane;
                R  += bp[(0+n2e)*64];
                Z  += bp[(2+n2e)*64];
                Ni += bp[(4+n2e)*64];
                Nh += bp[(6+n2e)*64];
            }
            const float bNh_ = s_bias[96+colL];
            #define EW(JJ, GR, GZ, GN, HOLD) { \
                const int j = jb2 + JJ; \
                float r, z, n; \
                if (g == TSTEPS){ \
                    r = sigmoidf_(R[j] + GR + s_bias[128+colL]); \
                    z = sigmoidf_(Z[j] + GZ + s_bias[160+colL]); \
                    n = tanhf_(GN + r*(Nh[j] + bNh_)); \
                } else { \
                    r = sigmoidf_(R[j] + s_bias[colL]); \
                    z = sigmoidf_(Z[j] + s_bias[32+colL]); \
                    n = tanhf_(Ni[j] + s_bias[64+colL] + r*(Nh[j] + bNh_)); \
                } \
                float hv = (1.0f - z)*n + z*HOLD; \
                unsigned short p1 = bf16_rne(hv); \
                unsigned short p0 = (unsigned short)((bf16_rne(hv - bf16_to_f(p1)) & 0xFFFCu) | otag); \
                store_sys_b32u(hout + (size_t)(bg*32 + r0 + JJ)*256 + ce, \
                               (((unsigned)p1) << 16) | (unsigned)p0); \
                HOLD = bf16_to_f(p1) + bf16_to_f(p0); }
            EW(0, gr0, gz0, gn0, hold0);
            EW(1, gr1, gz1, gn1, hold1);
            #undef EW
            if (lane == 0) store_sys_b32u(mycan, (unsigned)(g + 1));
        }

        // ---- out_{g-129} = H @ regW^T + regb ----
        if (g >= TSTEPS + 1 && wv == m_o){
            float rb = s_bias[192 + lcol];
            f32x4 ot = {rb, rb, rb, rb};
            #pragma unroll
            for (int k2 = 0; k2 < 4; ++k2)
                ot += s_outv[(size_t)(p*4 + k2)*64 + lane];
            const int oi = g - TSTEPS - 1;
            #pragma unroll
            for (int j = 0; j < 4; ++j)
                out[(size_t)(bg*32 + m_o*16 + quad*4 + j)*(TSTEPS*Fsz)
                    + (size_t)oi*Fsz + nc*16 + lcol] = ot[j];
        }
    }
}

extern "C" void kernel_launch(void* const* d_in, const int* in_sizes, int n_in,
                              void* d_out, int out_size, void* d_ws, size_t ws_size,
                              hipStream_t stream)
{
    (void)in_sizes; (void)n_in; (void)out_size; (void)ws_size;
    const float* x    = (const float*)d_in[0];
    const float* eWih = (const float*)d_in[1];
    const float* eWhh = (const float*)d_in[2];
    const float* ebih = (const float*)d_in[3];
    const float* ebhh = (const float*)d_in[4];
    const float* dWih = (const float*)d_in[5];
    const float* dWhh = (const float*)d_in[6];
    const float* dbih = (const float*)d_in[7];
    const float* dbhh = (const float*)d_in[8];
    const float* regW = (const float*)d_in[9];
    const float* regb = (const float*)d_in[10];
    float* out = (float*)d_out;

    unsigned* hbuf = (unsigned*)d_ws;                    // 2 slots of 512x256 packed bf16-pairs
    float* Mw    = (float*)d_ws + 2*Bsz*Hsz;             // 768*256
    float* gi0   = Mw + G3*Hsz;                          // 512*768
    float* cfold = gi0 + (size_t)Bsz*G3;                 // 768 (+pad)
    unsigned* canary = (unsigned*)(cfold + 1024);        // 16 bg x 64 wave-flags, 4B stride

    // slot0 = h^0 = 0 (tag 0 == tag(gen0)); slot1 = 0x03 bytes (tag 3 != tag(gen1)=0)
    hipMemsetAsync(hbuf, 0, (size_t)Bsz*Hsz*sizeof(unsigned), stream);
    hipMemsetAsync(hbuf + (size_t)Bsz*Hsz, 3, (size_t)Bsz*Hsz*sizeof(unsigned), stream);
    hipMemsetAsync(canary, 0, (size_t)BG*64*sizeof(unsigned), stream);

    hipLaunchKernelGGL(gru_setup, dim3(2307), dim3(256), 0, stream,
                       x, dWih, dbih, regW, regb, Mw, cfold, gi0);

    hipFuncSetAttribute((const void*)gru_persistent,
                        hipFuncAttributeMaxDynamicSharedMemorySize, SMEM_BYTES);

    void* args[] = { (void*)&x, (void*)&eWih, (void*)&eWhh, (void*)&ebih, (void*)&ebhh,
                     (void*)&dWhh, (void*)&dbhh, (void*)&Mw, (void*)&cfold, (void*)&gi0,
                     (void*)&regW, (void*)&regb, (void*)&hbuf, (void*)&canary, (void*)&out };
    hipError_t rc = hipLaunchCooperativeKernel((const void*)gru_persistent,
                                               dim3(NBLK), dim3(NTHR), args,
                                               SMEM_BYTES, stream);
    if (rc != hipSuccess) {
        hipLaunchKernelGGL(gru_persistent, dim3(NBLK), dim3(NTHR), SMEM_BYTES, stream,
                           x, eWih, eWhh, ebih, ebhh, dWhh, dbhh, Mw, cfold, gi0,
                           regW, regb, hbuf, canary, out);
    }
}